// Round 1
// baseline (174.269 us; speedup 1.0000x reference)
//
#include <hip/hip_runtime.h>
#include <math.h>

#define C_NUM 1000
#define M_MODES 10
#define CMTOT (C_NUM * M_MODES)   // 10000
#define D_FEAT 128
#define N_BATCH 1024

// workspace layout (floats)
#define OFF_SUMOH  0
#define OFF_WFEAT  10240
#define OFF_AVEN   (10240 + 1280000)            // 1,290,240
#define OFF_KAPPA  (OFF_AVEN + 1280000)         // 2,570,240
#define OFF_LOGC   (OFF_KAPPA + 10240)          // 2,580,480
#define ZERO_BYTES ((10240 + 1280000) * 4)      // sum_oh + wfeat

// log( I_63(x) * exp(-x) ) via uniform (Debye) asymptotic expansion, nu = 63.
// Valid for all x >= 0 at nu=63: rel. err ~ u3/nu^3 < 1e-8.
// Uses 63*sqrt(1+z^2) - x = nu^2 / (x + sqrt(x^2+nu^2)) to avoid cancellation.
__device__ __forceinline__ float log_ive63(float x) {
    float sw = sqrtf(fmaf(x, x, 3969.0f));        // sqrt(nu^2 + x^2)
    float t  = 63.0f / sw;
    float t2 = t * t;
    float u1 = t  * fmaf(-5.0f, t2, 3.0f) * (1.0f / 1512.0f);                  // u1(t)/nu
    float u2 = t2 * fmaf(t2, fmaf(385.0f, t2, -462.0f), 81.0f)
                  * (1.0f / 4572288.0f);                                       // u2(t)/nu^2
    float corr = u1 + u2;
    return 3969.0f / (x + sw)
         + 63.0f * logf(x / (63.0f + sw))
         - 0.5f * logf(6.283185307179586f * sw)
         + (corr - 0.5f * corr * corr);            // log1p(corr)
}

// ---------------- K1: soft assignment + label scatter (one wave per sample) --
__global__ __launch_bounds__(64) void k1_soft_assign(
    const float* __restrict__ feat,      // [1024][128]
    const float* __restrict__ ave_old,   // [1000][10][128]
    const int*   __restrict__ labels,    // [1024]
    float* __restrict__ sum_oh,          // [10000]
    float* __restrict__ wfeat)           // [10000][128]
{
    const int n = blockIdx.x;
    const int l = threadIdx.x;           // 0..63
    const int lab = labels[n];

    float2 f = ((const float2*)(feat + n * D_FEAT))[l];
    float fn = f.x * f.x + f.y * f.y;
    #pragma unroll
    for (int s = 1; s < 64; s <<= 1) fn += __shfl_xor(fn, s);
    const float fnorm = sqrtf(fn);

    float sc[M_MODES];
    #pragma unroll
    for (int m = 0; m < M_MODES; ++m) {
        float2 a = ((const float2*)(ave_old + (lab * M_MODES + m) * D_FEAT))[l];
        float d  = f.x * a.x + f.y * a.y;
        float an = a.x * a.x + a.y * a.y;
        #pragma unroll
        for (int s = 1; s < 64; s <<= 1) {
            d  += __shfl_xor(d, s);
            an += __shfl_xor(an, s);
        }
        float den = fmaxf(fnorm * sqrtf(an), 1e-8f);
        sc[m] = d / den;                 // TEMPERATURE = 1
    }
    // softmax over modes (identical in all lanes)
    float mx = sc[0];
    #pragma unroll
    for (int m = 1; m < M_MODES; ++m) mx = fmaxf(mx, sc[m]);
    float se = 0.f;
    #pragma unroll
    for (int m = 0; m < M_MODES; ++m) { sc[m] = expf(sc[m] - mx); se += sc[m]; }
    const float inv = 1.0f / se;

    #pragma unroll
    for (int m = 0; m < M_MODES; ++m) {
        float soft = sc[m] * inv;
        if (l == 0) atomicAdd(sum_oh + lab * M_MODES + m, soft);
        float* wrow = wfeat + (lab * M_MODES + m) * D_FEAT + 2 * l;
        atomicAdd(wrow + 0, soft * f.x);
        atomicAdd(wrow + 1, soft * f.y);
    }
}

// ---------------- K2: prototype update, kappa, logc, Ave_n (one wave per cm) -
__global__ __launch_bounds__(256) void k2_update(
    const float* __restrict__ ave_old,   // [10000][128]
    const float* __restrict__ amount,    // [10000]
    const float* __restrict__ sum_oh,    // [10000]
    const float* __restrict__ wfeat,     // [10000][128]
    float* __restrict__ ave_n,           // [10000][128]
    float* __restrict__ kap,             // [10000]
    float* __restrict__ logc)            // [10000]
{
    const int wid = blockIdx.x * 4 + (threadIdx.x >> 6);   // 0..9999
    const int l   = threadIdx.x & 63;

    const float s  = sum_oh[wid];
    const float am = amount[wid];
    const float w  = s / (s + am);                  // never NaN here (am=100)
    const float dn = (s == 0.0f) ? 1.0f : s;

    float2 wf = ((const float2*)(wfeat  + wid * D_FEAT))[l];
    float2 ao = ((const float2*)(ave_old + wid * D_FEAT))[l];
    float ax = ao.x * (1.0f - w) + (wf.x / dn) * w;
    float ay = ao.y * (1.0f - w) + (wf.y / dn) * w;

    float r2 = ax * ax + ay * ay;
    #pragma unroll
    for (int s2 = 1; s2 < 64; s2 <<= 1) r2 += __shfl_xor(r2, s2);
    const float R = sqrtf(r2);

    float kappa = 128.0f * R / (1.0f - R * R);
    if (kappa > 1e5f || kappa < 0.0f) kappa = 1e5f;

    const float lognu = log_ive63(kappa);
    const float lc = lognu + kappa - 63.0f * logf(kappa + 1e-20f);

    const float nrm = fmaxf(R, 1e-12f);
    ((float2*)(ave_n + wid * D_FEAT))[l] = make_float2(ax / nrm, ay / nrm);
    if (l == 0) { kap[wid] = kappa; logc[wid] = lc; }
}

// ---------------- K3: fused sims-GEMM + vMF logit + max over modes -----------
// tile: 64 n-rows x 80 cm-cols (= 8 whole classes); 256 threads;
// micro-tile 4n x 5cm per thread. LDS rows padded to 132 floats.
#define FSTRIDE 132
__global__ __launch_bounds__(256, 2) void k3_logits(
    const float* __restrict__ feat,      // [1024][128]
    const float* __restrict__ ave_n,     // [10000][128]
    const float* __restrict__ kap,       // [10000]
    const float* __restrict__ logc,      // [10000]
    float* __restrict__ out)             // [1024][1000]
{
    __shared__ float fT[64 * FSTRIDE];
    __shared__ float aT[80 * FSTRIDE];

    const int tid    = threadIdx.x;
    const int cmbase = blockIdx.x * 80;     // 125 tiles
    const int nbase  = blockIdx.y * 64;     // 16 tiles

    // stage features tile: 64 x 128 = 2048 float4
    for (int e = tid; e < 2048; e += 256) {
        float4 v = ((const float4*)(feat + nbase * D_FEAT))[e];
        int r = e >> 5, c4 = e & 31;
        *(float4*)(fT + r * FSTRIDE + c4 * 4) = v;
    }
    // stage Ave_n tile: 80 x 128 = 2560 float4
    for (int e = tid; e < 2560; e += 256) {
        float4 v = ((const float4*)(ave_n + cmbase * D_FEAT))[e];
        int r = e >> 5, c4 = e & 31;
        *(float4*)(aT + r * FSTRIDE + c4 * 4) = v;
    }
    __syncthreads();

    const int ng = tid >> 4;    // 0..15  -> 4 n-rows each
    const int cg = tid & 15;    // 0..15  -> 5 cm each

    float kf[5], lc[5];
    #pragma unroll
    for (int j = 0; j < 5; ++j) {
        kf[j] = kap[cmbase + cg * 5 + j];
        lc[j] = logc[cmbase + cg * 5 + j];
    }

    float acc[4][5] = {};
    const float* fb = fT + (ng * 4) * FSTRIDE;
    const float* ab = aT + (cg * 5) * FSTRIDE;

    #pragma unroll 2
    for (int k4 = 0; k4 < 32; ++k4) {
        float4 fa[4], av[5];
        #pragma unroll
        for (int i = 0; i < 4; ++i) fa[i] = *(const float4*)(fb + i * FSTRIDE + k4 * 4);
        #pragma unroll
        for (int j = 0; j < 5; ++j) av[j] = *(const float4*)(ab + j * FSTRIDE + k4 * 4);
        #pragma unroll
        for (int i = 0; i < 4; ++i)
            #pragma unroll
            for (int j = 0; j < 5; ++j) {
                acc[i][j] = fmaf(fa[i].x, av[j].x, acc[i][j]);
                acc[i][j] = fmaf(fa[i].y, av[j].y, acc[i][j]);
                acc[i][j] = fmaf(fa[i].z, av[j].z, acc[i][j]);
                acc[i][j] = fmaf(fa[i].w, av[j].w, acc[i][j]);
            }
    }

    // epilogue: kappa_new, logit, max over the 5 local modes
    float pm[4] = { -INFINITY, -INFINITY, -INFINITY, -INFINITY };
    #pragma unroll
    for (int j = 0; j < 5; ++j) {
        const float kfj = kf[j], lcj = lc[j];
        #pragma unroll
        for (int i = 0; i < 4; ++i) {
            float s   = acc[i][j];                               // sims (T=1)
            float kn2 = fmaf(kfj, kfj, fmaf(2.0f * s, kfj, 1.0f));
            float kn  = sqrtf(kn2);
            float lg  = log_ive63(kn) + kn - 63.0f * logf(kn + 1e-20f) - lcj;
            pm[i] = fmaxf(pm[i], lg);
        }
    }
    // combine the two half-mode threads (cg even/odd share a class)
    #pragma unroll
    for (int i = 0; i < 4; ++i) {
        float o = fmaxf(pm[i], __shfl_xor(pm[i], 1));
        if ((cg & 1) == 0) {
            int cls = blockIdx.x * 8 + (cg >> 1);
            out[(nbase + ng * 4 + i) * C_NUM + cls] = o;
        }
    }
}

extern "C" void kernel_launch(void* const* d_in, const int* in_sizes, int n_in,
                              void* d_out, int out_size, void* d_ws, size_t ws_size,
                              hipStream_t stream) {
    const float* feat    = (const float*)d_in[0];   // [1024*128]
    const float* ave_old = (const float*)d_in[1];   // [1000*10*128]
    const float* amount  = (const float*)d_in[2];   // [1000*10]
    const int*   labels  = (const int*)d_in[3];     // [1024]
    float* out = (float*)d_out;                     // [1024*1000]
    float* ws  = (float*)d_ws;

    float* sum_oh = ws + OFF_SUMOH;
    float* wfeat  = ws + OFF_WFEAT;
    float* aven   = ws + OFF_AVEN;
    float* kappa  = ws + OFF_KAPPA;
    float* logc   = ws + OFF_LOGC;

    (void)hipMemsetAsync(ws, 0, ZERO_BYTES, stream);

    k1_soft_assign<<<dim3(N_BATCH), dim3(64), 0, stream>>>(
        feat, ave_old, labels, sum_oh, wfeat);

    k2_update<<<dim3(CMTOT / 4), dim3(256), 0, stream>>>(
        ave_old, amount, sum_oh, wfeat, aven, kappa, logc);

    k3_logits<<<dim3(125, 16), dim3(256), 0, stream>>>(
        feat, aven, kappa, logc, out);
}

// Round 4
// 110.611 us; speedup vs baseline: 1.5755x; 1.5755x over previous
//
#include <hip/hip_runtime.h>
#include <math.h>

#define C_NUM 1000
#define M_MODES 10
#define CMTOT (C_NUM * M_MODES)   // 10000
#define D_FEAT 128
#define N_BATCH 1024

typedef _Float16 h16;
typedef h16 h16x2 __attribute__((ext_vector_type(2)));
typedef h16 half8 __attribute__((ext_vector_type(8)));
typedef float f32x4 __attribute__((ext_vector_type(4)));

// ---- workspace layout (float units) ----
#define OFF_CNT    0              // int[1024]           (memset to 0 each call)
#define OFF_IDX    1024           // int[1000*1024]
#define OFF_SOFT   1025024        // float[1024*10]
#define OFF_FEATH  1035264        // h16[1024*128]  = 65536 floats
#define OFF_AVEH   1100800        // h16[10000*128] = 640000 floats
#define OFF_KAPPA  1740800        // float[10000]
#define OFF_LOGC   1750800        // float[10000]
// total 1,760,800 floats = 7.04 MB

// logit core: given kn2 = kn^2 (kn = Bessel argument), returns
//   ln I63(kn) - 63 ln(kn)  =  sw - 63 ln(63+sw) - 0.5 ln(2*pi*sw) + log1p(corr)
// with sw = sqrt(kn2 + 63^2).  Uniform (Debye) asymptotic, rel err < 1e-8 at nu=63.
__device__ __forceinline__ float vmf_logterm(float kn2) {
    float sw2 = kn2 + 3969.0f;
    float sw  = sqrtf(sw2);
    float t2  = 3969.0f / sw2;
    float t   = 63.0f / sw;
    float u1 = t  * fmaf(-5.0f, t2, 3.0f) * (1.0f / 1512.0f);
    float u2 = t2 * fmaf(t2, fmaf(385.0f, t2, -462.0f), 81.0f) * (1.0f / 4572288.0f);
    float corr = u1 + u2;
    return sw - 63.0f * __logf(63.0f + sw)
              - 0.5f * __logf(6.283185307179586f * sw)
              + (corr - 0.5f * corr * corr);
}

// ---------------- K1: soft assignment + bucket insert (one wave per sample) --
__global__ __launch_bounds__(256) void k1_soft_assign(
    const float* __restrict__ feat,      // [1024][128]
    const float* __restrict__ ave_old,   // [1000][10][128]
    const int*   __restrict__ labels,    // [1024]
    int*   __restrict__ cnt,             // [1000] zeroed
    int*   __restrict__ idx,             // [1000][1024]
    float* __restrict__ soft,            // [1024][10]
    h16*   __restrict__ feat_h)          // [1024][128]
{
    const int n = blockIdx.x * 4 + (threadIdx.x >> 6);
    const int l = threadIdx.x & 63;
    const int lab = labels[n];

    float2 f = ((const float2*)(feat + n * D_FEAT))[l];
    ((h16x2*)(feat_h + n * D_FEAT))[l] = (h16x2){(h16)f.x, (h16)f.y};

    float fn = f.x * f.x + f.y * f.y;
    #pragma unroll
    for (int s = 1; s < 64; s <<= 1) fn += __shfl_xor(fn, s);
    const float fnorm = sqrtf(fn);

    float sc[M_MODES];
    #pragma unroll
    for (int m = 0; m < M_MODES; ++m) {
        float2 a = ((const float2*)(ave_old + (lab * M_MODES + m) * D_FEAT))[l];
        float d  = f.x * a.x + f.y * a.y;
        float an = a.x * a.x + a.y * a.y;
        #pragma unroll
        for (int s = 1; s < 64; s <<= 1) {
            d  += __shfl_xor(d, s);
            an += __shfl_xor(an, s);
        }
        float den = fmaxf(fnorm * sqrtf(an), 1e-8f);
        sc[m] = d / den;
    }
    float mx = sc[0];
    #pragma unroll
    for (int m = 1; m < M_MODES; ++m) mx = fmaxf(mx, sc[m]);
    float se = 0.f;
    #pragma unroll
    for (int m = 0; m < M_MODES; ++m) { sc[m] = __expf(sc[m] - mx); se += sc[m]; }
    const float inv = 1.0f / se;

    if (l == 0) {
        int pos = atomicAdd(cnt + lab, 1);
        idx[lab * 1024 + pos] = n;
        #pragma unroll
        for (int m = 0; m < M_MODES; ++m) soft[n * M_MODES + m] = sc[m] * inv;
    }
}

// ---------------- K2: gather-side CV update, kappa, logc, Ave_n fp16 ---------
__global__ __launch_bounds__(256) void k2_update(
    const float* __restrict__ feat,      // [1024][128]
    const float* __restrict__ ave_old,   // [10000][128]
    const float* __restrict__ amount,    // [10000]
    const int*   __restrict__ cnt,       // [1000]
    const int*   __restrict__ idx,       // [1000][1024]
    const float* __restrict__ soft,      // [1024][10]
    h16*   __restrict__ ave_h,           // [10000][128]
    float* __restrict__ kap,             // [10000]
    float* __restrict__ logc)            // [10000]
{
    const int wid = blockIdx.x * 4 + (threadIdx.x >> 6);   // 0..9999
    const int l   = threadIdx.x & 63;
    const int c   = wid / M_MODES;
    const int m   = wid - c * M_MODES;

    const int nc = cnt[c];
    float ssum = 0.f, wx = 0.f, wy = 0.f;
    for (int i = 0; i < nc; ++i) {
        int n = idx[c * 1024 + i];
        float s = soft[n * M_MODES + m];
        float2 f = ((const float2*)(feat + n * D_FEAT))[l];
        ssum += s;
        wx = fmaf(s, f.x, wx);
        wy = fmaf(s, f.y, wy);
    }

    const float am = amount[wid];
    float w = ssum / (ssum + am);
    if (!(w == w)) w = 0.0f;
    const float dn = (ssum == 0.0f) ? 1.0f : ssum;

    float2 ao = ((const float2*)(ave_old + wid * D_FEAT))[l];
    float ax = ao.x * (1.0f - w) + (wx / dn) * w;
    float ay = ao.y * (1.0f - w) + (wy / dn) * w;

    float r2 = ax * ax + ay * ay;
    #pragma unroll
    for (int s2 = 1; s2 < 64; s2 <<= 1) r2 += __shfl_xor(r2, s2);
    const float R = sqrtf(r2);

    float kappa = 128.0f * R / (1.0f - R * R);
    if (kappa > 1e5f || kappa < 0.0f) kappa = 1e5f;

    const float lc = vmf_logterm(kappa * kappa);

    const float nrm = fmaxf(R, 1e-12f);
    ((h16x2*)(ave_h + wid * D_FEAT))[l] = (h16x2){(h16)(ax / nrm), (h16)(ay / nrm)};
    if (l == 0) { kap[wid] = kappa; logc[wid] = lc; }
}

// ---------------- K3: f16 MFMA sims-GEMM + vMF logit + max over modes --------
// block tile: 64 n x 160 cm (16 classes); 4 waves, each 16 n x 160 cm.
// LDS rows padded to 136 halfs (272 B: 2-way bank alias = free).
#define AHS 136
#define LSTR 161
__global__ __launch_bounds__(256) void k3_logits(
    const h16*   __restrict__ feat_h,    // [1024][128]
    const h16*   __restrict__ ave_h,     // [10000][128]
    const float* __restrict__ kap,       // [10000]
    const float* __restrict__ logc,      // [10000]
    float* __restrict__ out)             // [1024][1000]
{
    __shared__ __align__(16) char smem[64 * AHS * 2 + 160 * AHS * 2]; // 60928 B
    h16*   aT = (h16*)smem;                    // [64][136]
    h16*   bT = (h16*)(smem + 64 * AHS * 2);   // [160][136]
    float* ls = (float*)smem;                  // [64][161] after barrier (41216 B)

    const int tid    = threadIdx.x;
    const int cmbase = blockIdx.x * 160;       // 63 tiles (last covers 80)
    const int nbase  = blockIdx.y * 64;

    // stage feature tile: 64 rows x 16 float4
    {
        const float4* src = (const float4*)(feat_h + nbase * D_FEAT);
        for (int e = tid; e < 1024; e += 256) {
            int r = e >> 4, c8 = e & 15;
            float4 v = src[e];
            *(float4*)(aT + r * AHS + c8 * 8) = v;
        }
    }
    // stage Ave_n tile: 160 rows x 16 float4 (clamp rows at the edge block)
    for (int e = tid; e < 2560; e += 256) {
        int r = e >> 4, c8 = e & 15;
        int row = cmbase + r; row = row < CMTOT ? row : CMTOT - 1;
        float4 v = *((const float4*)(ave_h + row * D_FEAT) + c8);
        *(float4*)(bT + r * AHS + c8 * 8) = v;
    }
    __syncthreads();

    const int wave = tid >> 6;
    const int lane = tid & 63;
    const int lrow = lane & 15;
    const int lhi  = lane >> 4;

    f32x4 acc[10] = {};
    #pragma unroll
    for (int ks = 0; ks < 4; ++ks) {
        half8 a = *(const half8*)(aT + (wave * 16 + lrow) * AHS + ks * 32 + lhi * 8);
        #pragma unroll
        for (int t = 0; t < 10; ++t) {
            half8 b = *(const half8*)(bT + (t * 16 + lrow) * AHS + ks * 32 + lhi * 8);
            acc[t] = __builtin_amdgcn_mfma_f32_16x16x32_f16(a, b, acc[t], 0, 0, 0);
        }
    }

    // epilogue in registers: acc[t][reg] -> logit
    #pragma unroll
    for (int t = 0; t < 10; ++t) {
        int cm = cmbase + t * 16 + lrow; cm = cm < CMTOT ? cm : CMTOT - 1;
        const float kf = kap[cm];
        const float lc = logc[cm];
        #pragma unroll
        for (int r = 0; r < 4; ++r) {
            float s   = acc[t][r];
            float kn2 = fmaf(kf, kf, fmaf(2.0f * s, kf, 1.0f));
            acc[t][r] = vmf_logterm(kn2) - lc;
        }
    }

    __syncthreads();   // all waves done reading aT/bT
    #pragma unroll
    for (int t = 0; t < 10; ++t)
        #pragma unroll
        for (int r = 0; r < 4; ++r)
            ls[(wave * 16 + lhi * 4 + r) * LSTR + t * 16 + lrow] = acc[t][r];
    __syncthreads();

    // max over the 10 modes of each class; 16 classes per block
    #pragma unroll
    for (int rep = 0; rep < 4; ++rep) {
        int row = rep * 16 + (tid >> 4);
        int c   = tid & 15;
        int cls = blockIdx.x * 16 + c;
        if (cls < C_NUM) {
            const float* p = ls + row * LSTR + c * 10;
            float mx = p[0];
            #pragma unroll
            for (int j = 1; j < 10; ++j) mx = fmaxf(mx, p[j]);
            out[(nbase + row) * C_NUM + cls] = mx;
        }
    }
}

extern "C" void kernel_launch(void* const* d_in, const int* in_sizes, int n_in,
                              void* d_out, int out_size, void* d_ws, size_t ws_size,
                              hipStream_t stream) {
    const float* feat    = (const float*)d_in[0];
    const float* ave_old = (const float*)d_in[1];
    const float* amount  = (const float*)d_in[2];
    const int*   labels  = (const int*)d_in[3];
    float* out = (float*)d_out;
    float* ws  = (float*)d_ws;

    int*   cnt    = (int*)(ws + OFF_CNT);
    int*   idx    = (int*)(ws + OFF_IDX);
    float* soft   = ws + OFF_SOFT;
    h16*   feat_h = (h16*)(ws + OFF_FEATH);
    h16*   ave_h  = (h16*)(ws + OFF_AVEH);
    float* kappa  = ws + OFF_KAPPA;
    float* logcv  = ws + OFF_LOGC;

    (void)hipMemsetAsync(cnt, 0, 1024 * sizeof(int), stream);

    k1_soft_assign<<<dim3(N_BATCH / 4), dim3(256), 0, stream>>>(
        feat, ave_old, labels, cnt, idx, soft, feat_h);

    k2_update<<<dim3(CMTOT / 4), dim3(256), 0, stream>>>(
        feat, ave_old, amount, cnt, idx, soft, ave_h, kappa, logcv);

    k3_logits<<<dim3(63, 16), dim3(256), 0, stream>>>(
        feat_h, ave_h, kappa, logcv, out);
}